// Round 2
// baseline (340.549 us; speedup 1.0000x reference)
//
#include <hip/hip_runtime.h>
#include <stdint.h>

// ---------------------------------------------------------------------------
// BNNLinear: out = BatchNorm( sign(x) @ sign(W)^T )
//   x: [M, K] f32, W: [N, K] f32, gamma/beta: [N] f32  ->  out: [M, N] f32
//
// Round 8 (on round 7's failed cooperative fusion):
//   - R7 post-mortem: absmax 5.375 == max|ref| -> output stayed memset-zero
//     -> hipLaunchCooperativeKernel was NOT graph-captured; kernel never ran.
//   - Fix: regular launch + hand-rolled one-shot grid barrier.
//     Co-residency proof: LDS 32KB/block -> 5 blocks/CU x 256 CU = 1280 >=
//     grid 1024, waves 20/CU <= 32, VGPR 64 -> no limit. No deadlock.
//   - Barrier counter in workspace, re-zeroed by binarize each launch
//     (stream-ordered), so graph replays are safe.
//   - Everything else identical to R6's proven GEMM (0 bank conflicts).
// ---------------------------------------------------------------------------

typedef int int32x4 __attribute__((ext_vector_type(4)));

#define BM 128
#define BN 128
#define BKI 128  // i8 k-bytes per LDS tile
#define EPS_BN 1e-5f

__device__ __forceinline__ void load16_lds(const void* g, void* l) {
  // 16B per lane, LDS dest = wave-uniform base + lane*16 (linear, no scatter)
  __builtin_amdgcn_global_load_lds(
      (const __attribute__((address_space(1))) void*)g,
      (__attribute__((address_space(3))) void*)l,
      16, 0, 0);
}

__device__ __forceinline__ char sgn(float v) {
  return v > 0.f ? (char)1 : (v < 0.f ? (char)-1 : (char)0);
}

// ---- 1) binarize f32 -> i8 sign (both tensors) + zero stats+barrier -------
__global__ void binarize_kernel(const float* __restrict__ x,
                                const float* __restrict__ w,
                                char* __restrict__ Ab, char* __restrict__ Bb,
                                float* __restrict__ stats,  // colSum|colSq|bar
                                int nx4, int ntot4, int n2) {
  int idx = blockIdx.x * blockDim.x + threadIdx.x;
  if (idx < n2) stats[idx] = 0.f;  // includes barrier counter (bit-zero)
  if (idx >= ntot4) return;
  const float4* src;
  char* dst;
  int i;
  if (idx < nx4) {
    src = reinterpret_cast<const float4*>(x); dst = Ab; i = idx;
  } else {
    src = reinterpret_cast<const float4*>(w); dst = Bb; i = idx - nx4;
  }
  float4 v = src[i];
  char4 o;
  o.x = sgn(v.x); o.y = sgn(v.y); o.z = sgn(v.z); o.w = sgn(v.w);
  reinterpret_cast<char4*>(dst)[i] = o;
}

// ---- 2) fused GEMM + BatchNorm (regular launch + manual grid barrier) -----
// C[i][j] = sum_k A[i][k]*Bt[j][k] (i8 -> i32 exact), then
// out = (C - mean_col) * gamma * rsqrt(var_col + eps) + beta, written f32.
// LDS swizzle: row r's 16B chunk c holds global k-chunk (c ^ (r&7)); staging
// applies the XOR on the global address (DMA dest stays linear); readers
// apply the same XOR. Measured round 5: SQ_LDS_BANK_CONFLICT == 0.
__global__ __launch_bounds__(256, 4) void gemm_bn_kernel(
    const char* __restrict__ A,    // [M][K] i8
    const char* __restrict__ Bt,   // [N][K] i8
    float* __restrict__ C,         // [M][N] f32 (final output)
    float* __restrict__ colSum,    // [N] (pre-zeroed)
    float* __restrict__ colSq,     // [N] (pre-zeroed)
    int* __restrict__ barrier,     // [1] (pre-zeroed)
    const float* __restrict__ gamma,
    const float* __restrict__ beta,
    int M, int N, int K) {
  __shared__ __align__(16) char sA[BM * BKI];  // 16 KiB
  __shared__ __align__(16) char sB[BN * BKI];  // 16 KiB

  const int tid  = threadIdx.x;
  const int wave = tid >> 6;
  const int lane = tid & 63;

  // consecutive block-ids share the same B panel (L2 locality)
  const int nby = M / BM;
  const int rowBlock = (blockIdx.x % nby) * BM;
  const int colBlock = (blockIdx.x / nby) * BN;

  // staging: per wave 32 rows A + 32 rows B; one call = 64 lanes x 16B
  // = 8 rows x 128B. 4 calls each.
  const int laneRow = lane >> 3;                 // 0..7 (== row & 7)
  const int c       = lane & 7;                  // chunk slot 0..7
  const int swz     = ((c ^ laneRow) & 7) * 16;  // global k-byte offset

  const char* Ag = A  + (size_t)(rowBlock + wave * 32 + laneRow) * K + swz;
  const char* Bg = Bt + (size_t)(colBlock + wave * 32 + laneRow) * K + swz;
  char* sAw = &sA[(wave * 32) * BKI];
  char* sBw = &sB[(wave * 32) * BKI];

  const int f    = lane & 15;  // m (A) / n (B) index
  const int quad = lane >> 4;  // k-group selector
  const int wr = (wave >> 1) * 64;
  const int wc = (wave & 1) * 64;
  const int f7 = f & 7;

  int32x4 acc[4][4] = {};

  for (int k0 = 0; k0 < K; k0 += BKI) {
    __syncthreads();  // prior ds_reads complete before overwrite
#pragma unroll
    for (int i = 0; i < 4; ++i) {
      load16_lds(Ag + k0 + (size_t)(i * 8) * K, sAw + i * 8 * BKI);
      load16_lds(Bg + k0 + (size_t)(i * 8) * K, sBw + i * 8 * BKI);
    }
    __syncthreads();  // vmcnt drain -> staging visible

#pragma unroll
    for (int s = 0; s < 2; ++s) {  // two K=64 sub-steps
      const int chunk = ((s * 4 + quad) ^ f7) * 16;
      int32x4 af[4], bfr[4];
#pragma unroll
      for (int mi = 0; mi < 4; ++mi)
        af[mi] = *reinterpret_cast<const int32x4*>(
            &sA[(wr + mi * 16 + f) * BKI + chunk]);
#pragma unroll
      for (int ni = 0; ni < 4; ++ni)
        bfr[ni] = *reinterpret_cast<const int32x4*>(
            &sB[(wc + ni * 16 + f) * BKI + chunk]);
#pragma unroll
      for (int mi = 0; mi < 4; ++mi)
#pragma unroll
        for (int ni = 0; ni < 4; ++ni)
          acc[mi][ni] = __builtin_amdgcn_mfma_i32_16x16x64_i8(
              af[mi], bfr[ni], acc[mi][ni], 0, 0, 0);
    }
  }

  // ---- column stats: C/D layout col = lane&15, row = quad*4 + reg ---------
  // per-column sum/sumsq (exact in f32 at these magnitudes), one atomic per
  // column per wave-half. Agent-scope atomics complete at the device
  // coherence point.
#pragma unroll
  for (int ni = 0; ni < 4; ++ni) {
    const int col = colBlock + wc + ni * 16 + f;
    float s = 0.f, sq = 0.f;
#pragma unroll
    for (int mi = 0; mi < 4; ++mi)
#pragma unroll
      for (int r = 0; r < 4; ++r) {
        const float fv = (float)acc[mi][ni][r];
        s += fv;
        sq += fv * fv;
      }
    s  += __shfl_xor(s, 16);  s  += __shfl_xor(s, 32);
    sq += __shfl_xor(sq, 16); sq += __shfl_xor(sq, 32);
    if (quad == 0) {
      atomicAdd(&colSum[col], s);
      atomicAdd(&colSq[col], sq);
    }
  }

  // ---- manual one-shot grid barrier ---------------------------------------
  // All 1024 blocks are co-resident (LDS: 5/CU x 256 = 1280 slots), so the
  // spin cannot deadlock. __syncthreads drains this block's atomics (vmcnt);
  // release-add arrival, acquire-spin until all arrived.
  __syncthreads();
  if (tid == 0) {
    __threadfence();  // device-scope release of this block's atomics
    __hip_atomic_fetch_add(barrier, 1, __ATOMIC_RELEASE,
                           __HIP_MEMORY_SCOPE_AGENT);
    const int nblk = (int)gridDim.x;
    while (__hip_atomic_load(barrier, __ATOMIC_ACQUIRE,
                             __HIP_MEMORY_SCOPE_AGENT) < nblk) {
      __builtin_amdgcn_s_sleep(2);
    }
  }
  __syncthreads();

  // ---- normalize in registers, write final f32 ----------------------------
  const float invM = 1.0f / (float)M;
#pragma unroll
  for (int ni = 0; ni < 4; ++ni) {
    const int col = colBlock + wc + ni * 16 + f;
    // agent-scope atomic loads: coherent view of other XCDs' atomics
    const float s  = __hip_atomic_load(&colSum[col], __ATOMIC_RELAXED,
                                       __HIP_MEMORY_SCOPE_AGENT);
    const float sq = __hip_atomic_load(&colSq[col], __ATOMIC_RELAXED,
                                       __HIP_MEMORY_SCOPE_AGENT);
    const float mu  = s * invM;
    const float var = sq * invM - mu * mu;
    const float sc  = gamma[col] * rsqrtf(var + EPS_BN);
    const float sh  = beta[col] - mu * sc;
#pragma unroll
    for (int mi = 0; mi < 4; ++mi) {
      float* Cp = C + (size_t)(rowBlock + wr + mi * 16 + quad * 4) * N + col;
#pragma unroll
      for (int r = 0; r < 4; ++r)
        Cp[(size_t)r * N] = (float)acc[mi][ni][r] * sc + sh;
    }
  }
}

// ---------------------------------------------------------------------------
extern "C" void kernel_launch(void* const* d_in, const int* in_sizes, int n_in,
                              void* d_out, int out_size, void* d_ws,
                              size_t ws_size, hipStream_t stream) {
  const float* x     = (const float*)d_in[0];
  const float* w     = (const float*)d_in[1];
  const float* gamma = (const float*)d_in[2];
  const float* beta  = (const float*)d_in[3];
  float* C = (float*)d_out;

  const int N = in_sizes[2];      // OUT
  const int K = in_sizes[1] / N;  // IN
  const int M = in_sizes[0] / K;  // batch

  // workspace: [A i8 M*K][B i8 N*K][colSum N][colSq N][barrier 1]
  char* ws = (char*)d_ws;
  char* Abin = ws;
  char* Bbin = ws + (size_t)M * K;
  float* stats = (float*)(ws + (size_t)M * K + (size_t)N * K);
  float* colSum = stats;
  float* colSq  = stats + N;
  int* barrier  = (int*)(stats + 2 * N);

  {
    int nx4 = (M * K) / 4;
    int ntot4 = (M * K + N * K) / 4;
    // zero colSum, colSq, and the barrier counter (2N+1 words)
    binarize_kernel<<<(ntot4 + 255) / 256, 256, 0, stream>>>(
        x, w, Abin, Bbin, stats, nx4, ntot4, 2 * N + 1);
  }

  {
    const int nTiles = (M / BM) * (N / BN);  // 1024 = 256 CUs x 4 blocks
    gemm_bn_kernel<<<nTiles, 256, 0, stream>>>(Abin, Bbin, C, colSum, colSq,
                                               barrier, gamma, beta, M, N, K);
  }
}

// Round 4
// 204.293 us; speedup vs baseline: 1.6670x; 1.6670x over previous
//
#include <hip/hip_runtime.h>
#include <stdint.h>

// ---------------------------------------------------------------------------
// BNNLinear: out = BatchNorm( sign(x) @ sign(W)^T )
//   x: [M, K] f32, W: [N, K] f32, gamma/beta: [N] f32  ->  out: [M, N] f32
//
// Round 10 = Round 9 with the compile fix:
//   __hip_atomic_thread_fence -> __builtin_amdgcn_fence(ACQUIRE, "agent").
//
// R9 design (untested due to compile error):
//   R8 post-mortem: acquire-load spin = per-iteration L2 invalidate storm
//   (1024 spinners x agent-scope acquire). MfmaUtil 5.8%/VALUBusy 3.7% ->
//   ~190us pure stall.
//   - Spin on RELAXED agent loads (still coherent: scope sets cache bypass,
//     ordering only adds fences), s_sleep(8) between polls; ONE acquire
//     fence after exit.
//   - Per-COLUMN-PANEL barriers (16 counters, 128B apart): each panel waits
//     only for its 64 row-blocks, not all 1024 blocks.
//   - Epilogue: threads 0..127 compute the block's 128 (scale,shift) pairs
//     once into LDS (aliased on sA, free after GEMM); all threads broadcast-
//     read. Cuts agent-scope stat loads 16x and rsqrtf 16x.
//   GEMM main loop identical to R6 (proven, 0 bank conflicts).
// ---------------------------------------------------------------------------

typedef int int32x4 __attribute__((ext_vector_type(4)));

#define BM 128
#define BN 128
#define BKI 128  // i8 k-bytes per LDS tile
#define EPS_BN 1e-5f
#define BAR_STRIDE 32  // ints between panel counters (128B, no false sharing)

__device__ __forceinline__ void load16_lds(const void* g, void* l) {
  // 16B per lane, LDS dest = wave-uniform base + lane*16 (linear, no scatter)
  __builtin_amdgcn_global_load_lds(
      (const __attribute__((address_space(1))) void*)g,
      (__attribute__((address_space(3))) void*)l,
      16, 0, 0);
}

__device__ __forceinline__ char sgn(float v) {
  return v > 0.f ? (char)1 : (v < 0.f ? (char)-1 : (char)0);
}

// ---- 1) binarize f32 -> i8 sign (both tensors) + zero stats+barriers ------
__global__ void binarize_kernel(const float* __restrict__ x,
                                const float* __restrict__ w,
                                char* __restrict__ Ab, char* __restrict__ Bb,
                                float* __restrict__ stats,  // colSum|colSq|bar
                                int nx4, int ntot4, int n2) {
  int idx = blockIdx.x * blockDim.x + threadIdx.x;
  if (idx < n2) stats[idx] = 0.f;  // 0.0f bit pattern == int 0
  if (idx >= ntot4) return;
  const float4* src;
  char* dst;
  int i;
  if (idx < nx4) {
    src = reinterpret_cast<const float4*>(x); dst = Ab; i = idx;
  } else {
    src = reinterpret_cast<const float4*>(w); dst = Bb; i = idx - nx4;
  }
  float4 v = src[i];
  char4 o;
  o.x = sgn(v.x); o.y = sgn(v.y); o.z = sgn(v.z); o.w = sgn(v.w);
  reinterpret_cast<char4*>(dst)[i] = o;
}

// ---- 2) fused GEMM + BatchNorm (manual per-panel grid barrier) ------------
// C[i][j] = sum_k A[i][k]*Bt[j][k] (i8 -> i32 exact), then
// out = (C - mean_col) * gamma * rsqrt(var_col + eps) + beta, written f32.
// LDS swizzle: row r's 16B chunk c holds global k-chunk (c ^ (r&7)); staging
// applies the XOR on the global address (DMA dest stays linear); readers
// apply the same XOR. Measured round 5: SQ_LDS_BANK_CONFLICT == 0.
__global__ __launch_bounds__(256, 4) void gemm_bn_kernel(
    const char* __restrict__ A,    // [M][K] i8
    const char* __restrict__ Bt,   // [N][K] i8
    float* __restrict__ C,         // [M][N] f32 (final output)
    float* __restrict__ colSum,    // [N] (pre-zeroed)
    float* __restrict__ colSq,     // [N] (pre-zeroed)
    int* __restrict__ barriers,    // [16 * BAR_STRIDE] (pre-zeroed)
    const float* __restrict__ gamma,
    const float* __restrict__ beta,
    int M, int N, int K) {
  __shared__ __align__(16) char sA[BM * BKI];  // 16 KiB
  __shared__ __align__(16) char sB[BN * BKI];  // 16 KiB

  const int tid  = threadIdx.x;
  const int wave = tid >> 6;
  const int lane = tid & 63;

  // consecutive block-ids share the same B panel (L2 locality)
  const int nby = M / BM;            // row-blocks per column panel (64)
  const int panel = blockIdx.x / nby;
  const int rowBlock = (blockIdx.x % nby) * BM;
  const int colBlock = panel * BN;

  // staging: per wave 32 rows A + 32 rows B; one call = 64 lanes x 16B
  // = 8 rows x 128B. 4 calls each.
  const int laneRow = lane >> 3;                 // 0..7 (== row & 7)
  const int c       = lane & 7;                  // chunk slot 0..7
  const int swz     = ((c ^ laneRow) & 7) * 16;  // global k-byte offset

  const char* Ag = A  + (size_t)(rowBlock + wave * 32 + laneRow) * K + swz;
  const char* Bg = Bt + (size_t)(colBlock + wave * 32 + laneRow) * K + swz;
  char* sAw = &sA[(wave * 32) * BKI];
  char* sBw = &sB[(wave * 32) * BKI];

  const int f    = lane & 15;  // m (A) / n (B) index
  const int quad = lane >> 4;  // k-group selector
  const int wr = (wave >> 1) * 64;
  const int wc = (wave & 1) * 64;
  const int f7 = f & 7;

  int32x4 acc[4][4] = {};

  for (int k0 = 0; k0 < K; k0 += BKI) {
    __syncthreads();  // prior ds_reads complete before overwrite
#pragma unroll
    for (int i = 0; i < 4; ++i) {
      load16_lds(Ag + k0 + (size_t)(i * 8) * K, sAw + i * 8 * BKI);
      load16_lds(Bg + k0 + (size_t)(i * 8) * K, sBw + i * 8 * BKI);
    }
    __syncthreads();  // vmcnt drain -> staging visible

#pragma unroll
    for (int s = 0; s < 2; ++s) {  // two K=64 sub-steps
      const int chunk = ((s * 4 + quad) ^ f7) * 16;
      int32x4 af[4], bfr[4];
#pragma unroll
      for (int mi = 0; mi < 4; ++mi)
        af[mi] = *reinterpret_cast<const int32x4*>(
            &sA[(wr + mi * 16 + f) * BKI + chunk]);
#pragma unroll
      for (int ni = 0; ni < 4; ++ni)
        bfr[ni] = *reinterpret_cast<const int32x4*>(
            &sB[(wc + ni * 16 + f) * BKI + chunk]);
#pragma unroll
      for (int mi = 0; mi < 4; ++mi)
#pragma unroll
        for (int ni = 0; ni < 4; ++ni)
          acc[mi][ni] = __builtin_amdgcn_mfma_i32_16x16x64_i8(
              af[mi], bfr[ni], acc[mi][ni], 0, 0, 0);
    }
  }

  // ---- column stats: C/D layout col = lane&15, row = quad*4 + reg ---------
  // per-column sum/sumsq; agent-scope atomics execute at the coherent point.
#pragma unroll
  for (int ni = 0; ni < 4; ++ni) {
    const int col = colBlock + wc + ni * 16 + f;
    float s = 0.f, sq = 0.f;
#pragma unroll
    for (int mi = 0; mi < 4; ++mi)
#pragma unroll
      for (int r = 0; r < 4; ++r) {
        const float fv = (float)acc[mi][ni][r];
        s += fv;
        sq += fv * fv;
      }
    s  += __shfl_xor(s, 16);  s  += __shfl_xor(s, 32);
    sq += __shfl_xor(sq, 16); sq += __shfl_xor(sq, 32);
    if (quad == 0) {
      atomicAdd(&colSum[col], s);
      atomicAdd(&colSq[col], sq);
    }
  }

  // ---- per-panel grid barrier --------------------------------------------
  // Panel p's columns are touched only by its own nby row-blocks. All 1024
  // blocks co-resident (LDS 32KB -> 5/CU x 256 = 1280 slots): no deadlock.
  // RELAXED spin (agent scope still reads the coherent point; no per-poll
  // cache invalidates) + single acquire fence after exit.
  __syncthreads();  // all waves' atomics issued; LDS reads done (sA reusable)
  if (tid == 0) {
    int* bar = barriers + panel * BAR_STRIDE;
    __hip_atomic_fetch_add(bar, 1, __ATOMIC_RELEASE,
                           __HIP_MEMORY_SCOPE_AGENT);
    while (__hip_atomic_load(bar, __ATOMIC_RELAXED,
                             __HIP_MEMORY_SCOPE_AGENT) < nby) {
      __builtin_amdgcn_s_sleep(8);
    }
    __builtin_amdgcn_fence(__ATOMIC_ACQUIRE, "agent");
  }
  __syncthreads();

  // ---- stage per-column (scale, shift) in LDS (aliased on sA) -------------
  float2* sSC = reinterpret_cast<float2*>(sA);  // 128 pairs = 1 KiB
  if (tid < BN) {
    const int col = colBlock + tid;
    const float s  = __hip_atomic_load(&colSum[col], __ATOMIC_RELAXED,
                                       __HIP_MEMORY_SCOPE_AGENT);
    const float sq = __hip_atomic_load(&colSq[col], __ATOMIC_RELAXED,
                                       __HIP_MEMORY_SCOPE_AGENT);
    const float invM = 1.0f / (float)M;
    const float mu  = s * invM;
    const float var = sq * invM - mu * mu;
    const float sc  = gamma[col] * rsqrtf(var + EPS_BN);
    const float sh  = beta[col] - mu * sc;
    sSC[tid] = make_float2(sc, sh);
  }
  __syncthreads();

  // ---- normalize in registers, write final f32 ----------------------------
#pragma unroll
  for (int ni = 0; ni < 4; ++ni) {
    const int lc  = wc + ni * 16 + f;  // block-local column
    const float2 ss = sSC[lc];
    const int col = colBlock + lc;
#pragma unroll
    for (int mi = 0; mi < 4; ++mi) {
      float* Cp = C + (size_t)(rowBlock + wr + mi * 16 + quad * 4) * N + col;
#pragma unroll
      for (int r = 0; r < 4; ++r)
        Cp[(size_t)r * N] = (float)acc[mi][ni][r] * ss.x + ss.y;
    }
  }
}

// ---------------------------------------------------------------------------
extern "C" void kernel_launch(void* const* d_in, const int* in_sizes, int n_in,
                              void* d_out, int out_size, void* d_ws,
                              size_t ws_size, hipStream_t stream) {
  const float* x     = (const float*)d_in[0];
  const float* w     = (const float*)d_in[1];
  const float* gamma = (const float*)d_in[2];
  const float* beta  = (const float*)d_in[3];
  float* C = (float*)d_out;

  const int N = in_sizes[2];      // OUT
  const int K = in_sizes[1] / N;  // IN
  const int M = in_sizes[0] / K;  // batch

  // workspace: [A i8 M*K][B i8 N*K][colSum N][colSq N][barriers 16*32 ints]
  char* ws = (char*)d_ws;
  char* Abin = ws;
  char* Bbin = ws + (size_t)M * K;
  float* stats = (float*)(ws + (size_t)M * K + (size_t)N * K);
  float* colSum = stats;
  float* colSq  = stats + N;
  int* barriers = (int*)(stats + 2 * N);

  {
    int nx4 = (M * K) / 4;
    int ntot4 = (M * K + N * K) / 4;
    // zero colSum, colSq, and the 16 padded barrier counters
    binarize_kernel<<<(ntot4 + 255) / 256, 256, 0, stream>>>(
        x, w, Abin, Bbin, stats, nx4, ntot4, 2 * N + 16 * BAR_STRIDE);
  }

  {
    const int nTiles = (M / BM) * (N / BN);  // 1024 = 256 CUs x 4 blocks
    gemm_bn_kernel<<<nTiles, 256, 0, stream>>>(Abin, Bbin, C, colSum, colSq,
                                               barriers, gamma, beta, M, N, K);
  }
}

// Round 5
// 172.026 us; speedup vs baseline: 1.9796x; 1.1876x over previous
//
#include <hip/hip_runtime.h>
#include <stdint.h>

// ---------------------------------------------------------------------------
// BNNLinear: out = BatchNorm( sign(x) @ sign(W)^T )
//   x: [M, K] f32, W: [N, K] f32, gamma/beta: [N] f32  ->  out: [M, N] f32
//
// Round 11 (on round 10's fused kernel, 87.9us):
//   R10 post-mortem: MFMA-busy unchanged (13.4us) but ~35us unexplained in
//   the barrier region. Theory: the per-block agent-scope RELEASE fetch_add
//   (L2 writeback) and ACQUIRE fence (L2 invalidate) evict co-resident
//   blocks' A/B panels mid-GEMM -> skew feedback. Same mechanism as R8's
//   per-poll invalidate, 1000x rarer but still ~35us.
//   Fix: NO hardware fences at all. All cross-block payload (colSum/colSq,
//   counter) moves via agent-scope ATOMIC OPS which execute at the coherent
//   point (L3) directly:
//     - producer: __syncthreads drains vmcnt (adds complete at L3) before
//       tid0's RELAXED counter add issues -> ordering guaranteed;
//     - consumer: relaxed spin -> compiler-only asm barrier -> agent-scope
//       relaxed atomic stat loads (read L3 directly, no invalidate needed).
//   Also: prefetch gamma/beta into regs before the spin (latency hidden
//   under the wait).
//   GEMM main loop identical to R6 (proven, 0 bank conflicts).
// ---------------------------------------------------------------------------

typedef int int32x4 __attribute__((ext_vector_type(4)));

#define BM 128
#define BN 128
#define BKI 128  // i8 k-bytes per LDS tile
#define EPS_BN 1e-5f
#define BAR_STRIDE 32  // ints between panel counters (128B, no false sharing)

__device__ __forceinline__ void load16_lds(const void* g, void* l) {
  // 16B per lane, LDS dest = wave-uniform base + lane*16 (linear, no scatter)
  __builtin_amdgcn_global_load_lds(
      (const __attribute__((address_space(1))) void*)g,
      (__attribute__((address_space(3))) void*)l,
      16, 0, 0);
}

__device__ __forceinline__ char sgn(float v) {
  return v > 0.f ? (char)1 : (v < 0.f ? (char)-1 : (char)0);
}

// ---- 1) binarize f32 -> i8 sign (both tensors) + zero stats+barriers ------
__global__ void binarize_kernel(const float* __restrict__ x,
                                const float* __restrict__ w,
                                char* __restrict__ Ab, char* __restrict__ Bb,
                                float* __restrict__ stats,  // colSum|colSq|bar
                                int nx4, int ntot4, int n2) {
  int idx = blockIdx.x * blockDim.x + threadIdx.x;
  if (idx < n2) stats[idx] = 0.f;  // 0.0f bit pattern == int 0
  if (idx >= ntot4) return;
  const float4* src;
  char* dst;
  int i;
  if (idx < nx4) {
    src = reinterpret_cast<const float4*>(x); dst = Ab; i = idx;
  } else {
    src = reinterpret_cast<const float4*>(w); dst = Bb; i = idx - nx4;
  }
  float4 v = src[i];
  char4 o;
  o.x = sgn(v.x); o.y = sgn(v.y); o.z = sgn(v.z); o.w = sgn(v.w);
  reinterpret_cast<char4*>(dst)[i] = o;
}

// ---- 2) fused GEMM + BatchNorm (manual per-panel grid barrier) ------------
// C[i][j] = sum_k A[i][k]*Bt[j][k] (i8 -> i32 exact), then
// out = (C - mean_col) * gamma * rsqrt(var_col + eps) + beta, written f32.
// LDS swizzle: row r's 16B chunk c holds global k-chunk (c ^ (r&7)); staging
// applies the XOR on the global address (DMA dest stays linear); readers
// apply the same XOR. Measured round 5: SQ_LDS_BANK_CONFLICT == 0.
__global__ __launch_bounds__(256, 4) void gemm_bn_kernel(
    const char* __restrict__ A,    // [M][K] i8
    const char* __restrict__ Bt,   // [N][K] i8
    float* __restrict__ C,         // [M][N] f32 (final output)
    float* __restrict__ colSum,    // [N] (pre-zeroed)
    float* __restrict__ colSq,     // [N] (pre-zeroed)
    int* __restrict__ barriers,    // [16 * BAR_STRIDE] (pre-zeroed)
    const float* __restrict__ gamma,
    const float* __restrict__ beta,
    int M, int N, int K) {
  __shared__ __align__(16) char sA[BM * BKI];  // 16 KiB
  __shared__ __align__(16) char sB[BN * BKI];  // 16 KiB

  const int tid  = threadIdx.x;
  const int wave = tid >> 6;
  const int lane = tid & 63;

  // consecutive block-ids share the same B panel (L2 locality)
  const int nby = M / BM;            // row-blocks per column panel (64)
  const int panel = blockIdx.x / nby;
  const int rowBlock = (blockIdx.x % nby) * BM;
  const int colBlock = panel * BN;

  // staging: per wave 32 rows A + 32 rows B; one call = 64 lanes x 16B
  // = 8 rows x 128B. 4 calls each.
  const int laneRow = lane >> 3;                 // 0..7 (== row & 7)
  const int c       = lane & 7;                  // chunk slot 0..7
  const int swz     = ((c ^ laneRow) & 7) * 16;  // global k-byte offset

  const char* Ag = A  + (size_t)(rowBlock + wave * 32 + laneRow) * K + swz;
  const char* Bg = Bt + (size_t)(colBlock + wave * 32 + laneRow) * K + swz;
  char* sAw = &sA[(wave * 32) * BKI];
  char* sBw = &sB[(wave * 32) * BKI];

  const int f    = lane & 15;  // m (A) / n (B) index
  const int quad = lane >> 4;  // k-group selector
  const int wr = (wave >> 1) * 64;
  const int wc = (wave & 1) * 64;
  const int f7 = f & 7;

  int32x4 acc[4][4] = {};

  for (int k0 = 0; k0 < K; k0 += BKI) {
    __syncthreads();  // prior ds_reads complete before overwrite
#pragma unroll
    for (int i = 0; i < 4; ++i) {
      load16_lds(Ag + k0 + (size_t)(i * 8) * K, sAw + i * 8 * BKI);
      load16_lds(Bg + k0 + (size_t)(i * 8) * K, sBw + i * 8 * BKI);
    }
    __syncthreads();  // vmcnt drain -> staging visible

#pragma unroll
    for (int s = 0; s < 2; ++s) {  // two K=64 sub-steps
      const int chunk = ((s * 4 + quad) ^ f7) * 16;
      int32x4 af[4], bfr[4];
#pragma unroll
      for (int mi = 0; mi < 4; ++mi)
        af[mi] = *reinterpret_cast<const int32x4*>(
            &sA[(wr + mi * 16 + f) * BKI + chunk]);
#pragma unroll
      for (int ni = 0; ni < 4; ++ni)
        bfr[ni] = *reinterpret_cast<const int32x4*>(
            &sB[(wc + ni * 16 + f) * BKI + chunk]);
#pragma unroll
      for (int mi = 0; mi < 4; ++mi)
#pragma unroll
        for (int ni = 0; ni < 4; ++ni)
          acc[mi][ni] = __builtin_amdgcn_mfma_i32_16x16x64_i8(
              af[mi], bfr[ni], acc[mi][ni], 0, 0, 0);
    }
  }

  // ---- column stats: C/D layout col = lane&15, row = quad*4 + reg ---------
  // per-column sum/sumsq; agent-scope atomics execute at the coherent point.
#pragma unroll
  for (int ni = 0; ni < 4; ++ni) {
    const int col = colBlock + wc + ni * 16 + f;
    float s = 0.f, sq = 0.f;
#pragma unroll
    for (int mi = 0; mi < 4; ++mi)
#pragma unroll
      for (int r = 0; r < 4; ++r) {
        const float fv = (float)acc[mi][ni][r];
        s += fv;
        sq += fv * fv;
      }
    s  += __shfl_xor(s, 16);  s  += __shfl_xor(s, 32);
    sq += __shfl_xor(sq, 16); sq += __shfl_xor(sq, 32);
    if (quad == 0) {
      atomicAdd(&colSum[col], s);
      atomicAdd(&colSq[col], sq);
    }
  }

  // prefetch gamma/beta for the epilogue (latency hides under the barrier)
  float gmv = 0.f, btv = 0.f;
  if (tid < BN) {
    gmv = gamma[colBlock + tid];
    btv = beta[colBlock + tid];
  }

  // ---- per-panel grid barrier --------------------------------------------
  // Panel p's columns are touched only by its own nby row-blocks. All 1024
  // blocks co-resident (LDS 32KB -> 5/CU x 256 = 1280 slots): no deadlock.
  // NO hardware fences: all cross-block payload moves via agent-scope atomic
  // ops at the coherent point. __syncthreads drained each wave's vmcnt (the
  // stat atomicAdds are complete at L3) before tid0's relaxed counter add.
  __syncthreads();
  if (tid == 0) {
    int* bar = barriers + panel * BAR_STRIDE;
    __hip_atomic_fetch_add(bar, 1, __ATOMIC_RELAXED,
                           __HIP_MEMORY_SCOPE_AGENT);
    while (__hip_atomic_load(bar, __ATOMIC_RELAXED,
                             __HIP_MEMORY_SCOPE_AGENT) < nby) {
      __builtin_amdgcn_s_sleep(8);
    }
    asm volatile("" ::: "memory");  // compiler-only ordering; no L2 inv
  }
  __syncthreads();

  // ---- stage per-column (scale, shift) in LDS (aliased on sA) -------------
  float2* sSC = reinterpret_cast<float2*>(sA);  // 128 pairs = 1 KiB
  if (tid < BN) {
    const int col = colBlock + tid;
    // agent-scope atomic loads read the coherent point (L3) directly
    const float s  = __hip_atomic_load(&colSum[col], __ATOMIC_RELAXED,
                                       __HIP_MEMORY_SCOPE_AGENT);
    const float sq = __hip_atomic_load(&colSq[col], __ATOMIC_RELAXED,
                                       __HIP_MEMORY_SCOPE_AGENT);
    const float invM = 1.0f / (float)M;
    const float mu  = s * invM;
    const float var = sq * invM - mu * mu;
    const float sc  = gmv * rsqrtf(var + EPS_BN);
    const float sh  = btv - mu * sc;
    sSC[tid] = make_float2(sc, sh);
  }
  __syncthreads();

  // ---- normalize in registers, write final f32 ----------------------------
#pragma unroll
  for (int ni = 0; ni < 4; ++ni) {
    const int lc  = wc + ni * 16 + f;  // block-local column
    const float2 ss = sSC[lc];
    const int col = colBlock + lc;
#pragma unroll
    for (int mi = 0; mi < 4; ++mi) {
      float* Cp = C + (size_t)(rowBlock + wr + mi * 16 + quad * 4) * N + col;
#pragma unroll
      for (int r = 0; r < 4; ++r)
        Cp[(size_t)r * N] = (float)acc[mi][ni][r] * ss.x + ss.y;
    }
  }
}

// ---------------------------------------------------------------------------
extern "C" void kernel_launch(void* const* d_in, const int* in_sizes, int n_in,
                              void* d_out, int out_size, void* d_ws,
                              size_t ws_size, hipStream_t stream) {
  const float* x     = (const float*)d_in[0];
  const float* w     = (const float*)d_in[1];
  const float* gamma = (const float*)d_in[2];
  const float* beta  = (const float*)d_in[3];
  float* C = (float*)d_out;

  const int N = in_sizes[2];      // OUT
  const int K = in_sizes[1] / N;  // IN
  const int M = in_sizes[0] / K;  // batch

  // workspace: [A i8 M*K][B i8 N*K][colSum N][colSq N][barriers 16*32 ints]
  char* ws = (char*)d_ws;
  char* Abin = ws;
  char* Bbin = ws + (size_t)M * K;
  float* stats = (float*)(ws + (size_t)M * K + (size_t)N * K);
  float* colSum = stats;
  float* colSq  = stats + N;
  int* barriers = (int*)(stats + 2 * N);

  {
    int nx4 = (M * K) / 4;
    int ntot4 = (M * K + N * K) / 4;
    // zero colSum, colSq, and the 16 padded barrier counters
    binarize_kernel<<<(ntot4 + 255) / 256, 256, 0, stream>>>(
        x, w, Abin, Bbin, stats, nx4, ntot4, 2 * N + 16 * BAR_STRIDE);
  }

  {
    const int nTiles = (M / BM) * (N / BN);  // 1024 = 256 CUs x 4 blocks
    gemm_bn_kernel<<<nTiles, 256, 0, stream>>>(Abin, Bbin, C, colSum, colSq,
                                               barriers, gamma, beta, M, N, K);
  }
}

// Round 6
// 165.115 us; speedup vs baseline: 2.0625x; 1.0419x over previous
//
#include <hip/hip_runtime.h>
#include <stdint.h>

// ---------------------------------------------------------------------------
// BNNLinear: out = BatchNorm( sign(x) @ sign(W)^T )
//   x: [M, K] f32, W: [N, K] f32, gamma/beta: [N] f32  ->  out: [M, N] f32
//
// Round 12 (on round 11's fused kernel, 57.4us, total 172us):
//   R11 post-mortem: prediction matched (57.4 in 55-62). GEMM phase is at
//   the documented m97-structure ceiling (37% of i8 peak). Only proven
//   escape: 256^2 8-phase schedule (T3+T4+T5). This round ports it to i8:
//   - BM=BN=256, BKI=128B, 512 thr (8 waves 2Mx4N), per-wave out 128x64.
//   - LDS 2x(32K+32K)=128KiB -> 1 block/CU, grid 256 = 1/CU exactly.
//   - Per K-tile: 4 phases {ds_read quadrant || 2x global_load_lds next
//     tile} -> s_barrier -> setprio(1) 16 MFMA setprio(0) -> s_barrier.
//   - Tile boundary: one __syncthreads (its vmcnt(0) is effectively
//     counted: only the current tile's 8 loads are outstanding, issued a
//     full tile-compute earlier). Loads stay in flight across the 8
//     intra-tile barriers = the T3/T4 overlap.
//   - Proven XOR swizzle unchanged (0 bank conflicts); fused-BN epilogue
//     + per-panel no-fence spin barrier unchanged from R11.
// ---------------------------------------------------------------------------

typedef int int32x4 __attribute__((ext_vector_type(4)));

#define BM 256
#define BN 256
#define BKI 128  // i8 k-bytes per LDS tile
#define EPS_BN 1e-5f
#define BAR_STRIDE 32  // ints between panel counters (128B, no false sharing)

__device__ __forceinline__ void load16_lds(const void* g, void* l) {
  // 16B per lane, LDS dest = wave-uniform base + lane*16 (linear, no scatter)
  __builtin_amdgcn_global_load_lds(
      (const __attribute__((address_space(1))) void*)g,
      (__attribute__((address_space(3))) void*)l,
      16, 0, 0);
}

__device__ __forceinline__ char sgn(float v) {
  return v > 0.f ? (char)1 : (v < 0.f ? (char)-1 : (char)0);
}

// ---- 1) binarize f32 -> i8 sign (both tensors) + zero stats+barriers ------
__global__ void binarize_kernel(const float* __restrict__ x,
                                const float* __restrict__ w,
                                char* __restrict__ Ab, char* __restrict__ Bb,
                                float* __restrict__ stats,  // colSum|colSq|bar
                                int nx4, int ntot4, int n2) {
  int idx = blockIdx.x * blockDim.x + threadIdx.x;
  if (idx < n2) stats[idx] = 0.f;  // 0.0f bit pattern == int 0
  if (idx >= ntot4) return;
  const float4* src;
  char* dst;
  int i;
  if (idx < nx4) {
    src = reinterpret_cast<const float4*>(x); dst = Ab; i = idx;
  } else {
    src = reinterpret_cast<const float4*>(w); dst = Bb; i = idx - nx4;
  }
  float4 v = src[i];
  char4 o;
  o.x = sgn(v.x); o.y = sgn(v.y); o.z = sgn(v.z); o.w = sgn(v.w);
  reinterpret_cast<char4*>(dst)[i] = o;
}

// ---- 2) fused GEMM + BatchNorm, 256^2 8-phase schedule --------------------
// C[i][j] = sum_k A[i][k]*Bt[j][k] (i8 -> i32 exact), then
// out = (C - mean_col) * gamma * rsqrt(var_col + eps) + beta, written f32.
// LDS swizzle: row r's 16B chunk c holds global k-chunk (c ^ (r&7)); staging
// applies the XOR on the global address (DMA dest stays linear); readers
// apply the same XOR. Proven 0 bank conflicts (identical row stride/read
// pattern as the 128^2 version).
__global__ __launch_bounds__(512, 2) void gemm_bn_kernel(
    const char* __restrict__ A,    // [M][K] i8
    const char* __restrict__ Bt,   // [N][K] i8
    float* __restrict__ C,         // [M][N] f32 (final output)
    float* __restrict__ colSum,    // [N] (pre-zeroed)
    float* __restrict__ colSq,     // [N] (pre-zeroed)
    int* __restrict__ barriers,    // [16 * BAR_STRIDE] (pre-zeroed)
    const float* __restrict__ gamma,
    const float* __restrict__ beta,
    int M, int N, int K) {
  __shared__ __align__(16) char sA[2][BM * BKI];  // 2 x 32 KiB
  __shared__ __align__(16) char sB[2][BN * BKI];  // 2 x 32 KiB  (128 KiB tot)

  const int tid  = threadIdx.x;
  const int wave = tid >> 6;
  const int lane = tid & 63;

  // consecutive block-ids share the same B panel (L2 locality)
  const int nby = M / BM;            // row-blocks per column panel (32)
  const int panel = blockIdx.x / nby;
  const int rowBlock = (blockIdx.x % nby) * BM;
  const int colBlock = panel * BN;

  // staging: each wave stages rows [wave*32, wave*32+32) of A and of B.
  // One call = 64 lanes x 16B = 8 rows x 128B; 4 calls per tensor per tile.
  const int laneRow = lane >> 3;                 // 0..7 (== row & 7)
  const int cch     = lane & 7;                  // chunk slot 0..7
  const int swz     = ((cch ^ laneRow) & 7) * 16;  // global k-byte offset

  const char* Ag = A  + (size_t)(rowBlock + wave * 32 + laneRow) * K + swz;
  const char* Bg = Bt + (size_t)(colBlock + wave * 32 + laneRow) * K + swz;

  const int f    = lane & 15;  // m (A) / n (B) index within fragment
  const int quad = lane >> 4;  // k-group selector
  const int f7   = f & 7;
  const int wm = (wave >> 2) * 128;  // wave M-origin (2 waves in M)
  const int wn = (wave & 3) * 64;    // wave N-origin (4 waves in N)

  int32x4 acc[8][4] = {};  // [im 0..7][in 0..3] -> 128 x 16x16 tile

  const int NT = K / BKI;  // 16 K-tiles

  // prologue: stage tile 0 into buffer 0 (8 calls per wave)
#pragma unroll
  for (int j = 0; j < 4; ++j) {
    load16_lds(Ag + (size_t)(j * 8) * K, &sA[0][(wave * 32 + j * 8) * BKI]);
    load16_lds(Bg + (size_t)(j * 8) * K, &sB[0][(wave * 32 + j * 8) * BKI]);
  }

  for (int t = 0; t < NT; ++t) {
    const int cur = t & 1;
    const int nxt = cur ^ 1;
    const char* sAc = sA[cur];
    const char* sBc = sB[cur];
    const size_t gkn = (size_t)(t + 1) * BKI;
    const bool pre = (t + 1 < NT);

    // tile boundary: compiler emits s_waitcnt vmcnt(0)+lgkmcnt(0)+s_barrier.
    // Outstanding vmem == this tile's 8 loads, issued one full tile-compute
    // ago -> the drain is effectively a counted wait (T4 in spirit).
    __syncthreads();

    int32x4 af[4][2];  // A-frags for current M-half, reused across 2 phases
#pragma unroll
    for (int q = 0; q < 4; ++q) {  // phase: (mh,nh) quadrant of wave output
      const int mh = q >> 1, nh = q & 1;
      if (nh == 0) {
#pragma unroll
        for (int mi = 0; mi < 4; ++mi)
#pragma unroll
          for (int s = 0; s < 2; ++s)
            af[mi][s] = *reinterpret_cast<const int32x4*>(
                &sAc[(wm + mh * 64 + mi * 16 + f) * BKI +
                     (((s * 4 + quad) ^ f7) * 16)]);
      }
      int32x4 bf_[2][2];
#pragma unroll
      for (int ni = 0; ni < 2; ++ni)
#pragma unroll
        for (int s = 0; s < 2; ++s)
          bf_[ni][s] = *reinterpret_cast<const int32x4*>(
              &sBc[(wn + nh * 32 + ni * 16 + f) * BKI +
                   (((s * 4 + quad) ^ f7) * 16)]);

      // issue 2 staging calls for tile t+1 (stay in flight across barriers)
      if (pre) {
        if (q < 2) {
#pragma unroll
          for (int j = 0; j < 2; ++j) {
            const int part = q * 2 + j;
            load16_lds(Ag + gkn + (size_t)(part * 8) * K,
                       &sA[nxt][(wave * 32 + part * 8) * BKI]);
          }
        } else {
#pragma unroll
          for (int j = 0; j < 2; ++j) {
            const int part = (q - 2) * 2 + j;
            load16_lds(Bg + gkn + (size_t)(part * 8) * K,
                       &sB[nxt][(wave * 32 + part * 8) * BKI]);
          }
        }
      }

      __builtin_amdgcn_s_barrier();  // raw: no vmcnt drain (loads in flight)
      __builtin_amdgcn_s_setprio(1);
#pragma unroll
      for (int mi = 0; mi < 4; ++mi)
#pragma unroll
        for (int ni = 0; ni < 2; ++ni)
#pragma unroll
          for (int s = 0; s < 2; ++s)
            acc[mh * 4 + mi][nh * 2 + ni] =
                __builtin_amdgcn_mfma_i32_16x16x64_i8(
                    af[mi][s], bf_[ni][s], acc[mh * 4 + mi][nh * 2 + ni],
                    0, 0, 0);
      __builtin_amdgcn_s_setprio(0);
      __builtin_amdgcn_s_barrier();
    }
  }

  // ---- column stats: C/D layout col = lane&15, row = quad*4 + reg ---------
#pragma unroll
  for (int in = 0; in < 4; ++in) {
    const int col = colBlock + wn + in * 16 + f;
    float s = 0.f, sq = 0.f;
#pragma unroll
    for (int im = 0; im < 8; ++im)
#pragma unroll
      for (int r = 0; r < 4; ++r) {
        const float fv = (float)acc[im][in][r];
        s += fv;
        sq += fv * fv;
      }
    s  += __shfl_xor(s, 16);  s  += __shfl_xor(s, 32);
    sq += __shfl_xor(sq, 16); sq += __shfl_xor(sq, 32);
    if (quad == 0) {
      atomicAdd(&colSum[col], s);
      atomicAdd(&colSq[col], sq);
    }
  }

  // prefetch gamma/beta for the epilogue (latency hides under the barrier)
  float gmv = 0.f, btv = 0.f;
  if (tid < BN) {
    gmv = gamma[colBlock + tid];
    btv = beta[colBlock + tid];
  }

  // ---- per-panel grid barrier (no HW fences; R11-proven) ------------------
  // Panel p's columns touched only by its own nby row-blocks. All 256
  // blocks co-resident (128KiB LDS -> 1 block/CU x 256 CUs): no deadlock.
  __syncthreads();  // drains vmcnt: this block's stat atomics done at L3
  if (tid == 0) {
    int* bar = barriers + panel * BAR_STRIDE;
    __hip_atomic_fetch_add(bar, 1, __ATOMIC_RELAXED,
                           __HIP_MEMORY_SCOPE_AGENT);
    while (__hip_atomic_load(bar, __ATOMIC_RELAXED,
                             __HIP_MEMORY_SCOPE_AGENT) < nby) {
      __builtin_amdgcn_s_sleep(8);
    }
    asm volatile("" ::: "memory");  // compiler-only ordering; no L2 inv
  }
  __syncthreads();

  // ---- stage per-column (scale, shift) in LDS (aliased on sA) -------------
  float2* sSC = reinterpret_cast<float2*>(&sA[0][0]);  // 256 pairs = 2 KiB
  if (tid < BN) {
    const int col = colBlock + tid;
    const float s  = __hip_atomic_load(&colSum[col], __ATOMIC_RELAXED,
                                       __HIP_MEMORY_SCOPE_AGENT);
    const float sq = __hip_atomic_load(&colSq[col], __ATOMIC_RELAXED,
                                       __HIP_MEMORY_SCOPE_AGENT);
    const float invM = 1.0f / (float)M;
    const float mu  = s * invM;
    const float var = sq * invM - mu * mu;
    const float sc  = gmv * rsqrtf(var + EPS_BN);
    const float sh  = btv - mu * sc;
    sSC[tid] = make_float2(sc, sh);
  }
  __syncthreads();

  // ---- normalize in registers, write final f32 ----------------------------
#pragma unroll
  for (int in = 0; in < 4; ++in) {
    const int lc  = wn + in * 16 + f;  // block-local column
    const float2 ss = sSC[lc];
    const int col = colBlock + lc;
#pragma unroll
    for (int im = 0; im < 8; ++im) {
      float* Cp = C + (size_t)(rowBlock + wm + im * 16 + quad * 4) * N + col;
#pragma unroll
      for (int r = 0; r < 4; ++r)
        Cp[(size_t)r * N] = (float)acc[im][in][r] * ss.x + ss.y;
    }
  }
}

// ---------------------------------------------------------------------------
extern "C" void kernel_launch(void* const* d_in, const int* in_sizes, int n_in,
                              void* d_out, int out_size, void* d_ws,
                              size_t ws_size, hipStream_t stream) {
  const float* x     = (const float*)d_in[0];
  const float* w     = (const float*)d_in[1];
  const float* gamma = (const float*)d_in[2];
  const float* beta  = (const float*)d_in[3];
  float* C = (float*)d_out;

  const int N = in_sizes[2];      // OUT
  const int K = in_sizes[1] / N;  // IN
  const int M = in_sizes[0] / K;  // batch

  // workspace: [A i8 M*K][B i8 N*K][colSum N][colSq N][barriers 16*32 ints]
  char* ws = (char*)d_ws;
  char* Abin = ws;
  char* Bbin = ws + (size_t)M * K;
  float* stats = (float*)(ws + (size_t)M * K + (size_t)N * K);
  float* colSum = stats;
  float* colSq  = stats + N;
  int* barriers = (int*)(stats + 2 * N);

  {
    int nx4 = (M * K) / 4;
    int ntot4 = (M * K + N * K) / 4;
    // zero colSum, colSq, and the 16 padded barrier counters
    binarize_kernel<<<(ntot4 + 255) / 256, 256, 0, stream>>>(
        x, w, Abin, Bbin, stats, nx4, ntot4, 2 * N + 16 * BAR_STRIDE);
  }

  {
    const int nTiles = (M / BM) * (N / BN);  // 256 = 256 CUs x 1 block
    gemm_bn_kernel<<<nTiles, 512, 0, stream>>>(Abin, Bbin, C, colSum, colSq,
                                               barriers, gamma, beta, M, N, K);
  }
}